// Round 15
// baseline (84.293 us; speedup 1.0000x reference)
//
#include <hip/hip_runtime.h>
#include <hip/hip_bf16.h>

// UniTeacherEncoder v15: v14 with the staging->fragment-read race FIXED
// (v14 dropped the post-staging barrier on a false wave-locality claim:
// thread t stages row i2*32 + t/8, but wave w reads rows 16w..16w+15).
// Structure: single-shot K/V staging + LDS CPB table + V-reg prefetch, 7 barriers.
// Fragment convention HW-verified (v10..v13 pass).
// __launch_bounds__(256,2) on hot kernels (only spill-free allocator config).

namespace {

constexpr int kN  = 1024;
constexpr int kC  = 128;
constexpr int kG  = 8;
constexpr int kDH = 64;
constexpr int kND = 256;

constexpr int   kNT    = 2048;      // CPB table intervals (PWL -> err ~5e-8)
constexpr float kRLO   = -2.0625f;  // rel in [-2.032, 2.032] guaranteed (|off|<=4)
constexpr float kRSPAN = 4.125f;

// workspace layout (float offsets)
constexpr size_t W_LNKV = 0;          // 2048 x 128 f32
constexpr size_t W_LNQ1 = 262144;
constexpr size_t W_LNQ2 = 524288;
constexpr size_t W_Q    = 786432;     // bf16 [32 bg][1024 r][64 d] row-major
constexpr size_t W_K    = 1835008;    // bf16 [32 bg][256 j][64 d] row-major
constexpr size_t W_VT   = 2097152;    // bf16 [32 bg][64 d][256 j] (transposed V)
constexpr size_t W_VGS  = 2359296;    // f32 [32][256]
constexpr size_t W_AO   = 2367488;    // bf16 [2 str][2048 tok][512 c]
constexpr size_t W_TAB  = 5251072;    // f32 2 x 2049
constexpr size_t W_MOUT = 5283844;    // 4 x 128
constexpr size_t W_PART = 5284356;    // 4 x 64 x 128
constexpr size_t W_OWB  = 5317124;    // bf16 2x128x512
constexpr size_t W_FWB  = 5382660;    // bf16 128x256

} // namespace

typedef __attribute__((ext_vector_type(8))) short short8;
typedef __attribute__((ext_vector_type(4))) float floatx4;

__device__ __forceinline__ float wave_sum(float v) {
#pragma unroll
  for (int o = 32; o > 0; o >>= 1) v += __shfl_xor(v, o, 64);
  return v;
}
__device__ __forceinline__ float cpb_lds(const float* __restrict__ tabL,
                                         float seq, float vg) {
  float rel = seq - vg;
  float ft = (rel - kRLO) * ((float)kNT / kRSPAN);
  ft = fminf(fmaxf(ft, 0.f), (float)kNT - 0.001f);
  int ix = (int)ft;
  float fw = ft - (float)ix;
  return tabL[ix] * (1.f - fw) + tabL[ix + 1] * fw;
}

// ---------------- k_prep: weight bf16 cvt + LN x3 + CPB table + mout ----------------
__global__ void k_prep(const float* __restrict__ ow, const float* __restrict__ fw,
                       __hip_bfloat16* __restrict__ owb, __hip_bfloat16* __restrict__ fwb,
                       const float* __restrict__ x1_0, const float* __restrict__ x1_1,
                       const float* __restrict__ x2, float* __restrict__ lnq1,
                       float* __restrict__ lnq2, float* __restrict__ lnkv,
                       const float* __restrict__ ng, const float* __restrict__ nb,
                       const float* __restrict__ cw1, const float* __restrict__ cb1,
                       const float* __restrict__ cw2, const float* __restrict__ cb2,
                       const float* __restrict__ cw3, const float* __restrict__ cb3,
                       float* __restrict__ tab,
                       const float* __restrict__ tfng, const float* __restrict__ tfnb,
                       const float* __restrict__ inw, const float* __restrict__ inb,
                       const float* __restrict__ tow, const float* __restrict__ tob,
                       float* __restrict__ mout) {
  int bx = blockIdx.x;
  int t = threadIdx.x;
  if (bx < 640) {
    int id = bx * 256 + t;
    if (id < 131072) owb[id] = __float2bfloat16(ow[id]);
    else fwb[id - 131072] = __float2bfloat16(fw[id - 131072]);
  } else if (bx < 2176) {
    int w = t >> 6, lane = t & 63;
    int gr = (bx - 640) * 4 + w;
    int sel = gr >> 11, row = gr & 2047;
    const float* in = (sel == 0) ? x1_0 : (sel == 1) ? x1_1 : x2;
    float* out = (sel == 0) ? lnq1 : (sel == 1) ? lnq2 : lnkv;
    const float* xr = in + (size_t)row * kC;
    float xa = xr[lane], xb = xr[lane + 64];
    float m = wave_sum(xa + xb) * (1.f / kC);
    float da = xa - m, db = xb - m;
    float v = wave_sum(da * da + db * db) * (1.f / kC);
    float r = rsqrtf(v + 1e-5f);
    float* orow = out + (size_t)row * kC;
    orow[lane]      = da * r * ng[lane] + nb[lane];
    orow[lane + 64] = db * r * ng[lane + 64] + nb[lane + 64];
  } else if (bx < 2194) {
    int rel = bx - 2176;
    int idx = rel / 9, bb = rel - idx * 9;
    int tt = bb * 256 + t;
    if (tt <= kNT) {
      float rel_ = kRLO + (kRSPAN / (float)kNT) * (float)tt;
      float u = (rel_ >= 0.f ? 1.f : -1.f) * log1pf(fabsf(rel_));
      const float* W1 = cw1 + idx * 32; const float* B1 = cb1 + idx * 32;
      const float* W2 = cw2 + idx * 1024; const float* B2 = cb2 + idx * 32;
      const float* W3 = cw3 + idx * 32; const float* B3 = cb3 + idx;
      float h1[32];
#pragma unroll
      for (int m = 0; m < 32; ++m) h1[m] = fmaxf(0.f, u * W1[m] + B1[m]);
      float o = B3[0];
      for (int m = 0; m < 32; ++m) {
        float a = B2[m];
#pragma unroll
        for (int k = 0; k < 32; ++k) a += h1[k] * W2[k * 32 + m];
        o += fmaxf(a, 0.f) * W3[m];
      }
      tab[(size_t)idx * (kNT + 1) + tt] = o;
    }
  } else {
    int rel = bx - 2194;
    int i = rel >> 1, b = rel & 1;
    bool act = t < 128;
    __shared__ float red[2];
    __shared__ float s1[128];
    __shared__ float s2[128];
    const float* xs = (i ? x1_1 : x1_0) + (size_t)b * kN * kC;
    float x = act ? xs[t] : 0.f;
    float s = wave_sum(x);
    if (act && (t & 63) == 0) red[t >> 6] = s;
    __syncthreads();
    float m1 = (red[0] + red[1]) * (1.f / kC);
    __syncthreads();
    float d1 = x - m1;
    float ss = wave_sum(act ? d1 * d1 : 0.f);
    if (act && (t & 63) == 0) red[t >> 6] = ss;
    __syncthreads();
    float v1 = (red[0] + red[1]) * (1.f / kC);
    __syncthreads();
    float t0 = act ? d1 * rsqrtf(v1 + 1e-5f) * ng[t] + nb[t] : 0.f;
    s = wave_sum(t0);
    if (act && (t & 63) == 0) red[t >> 6] = s;
    __syncthreads();
    float m2 = (red[0] + red[1]) * (1.f / kC);
    __syncthreads();
    float d2 = t0 - m2;
    ss = wave_sum(act ? d2 * d2 : 0.f);
    if (act && (t & 63) == 0) red[t >> 6] = ss;
    __syncthreads();
    float v2 = (red[0] + red[1]) * (1.f / kC);
    if (act) s1[t] = d2 * rsqrtf(v2 + 1e-5f) * tfng[i * kC + t] + tfnb[i * kC + t];
    __syncthreads();
    if (act) {
      float a0 = 0.f;
      const float* wr = inw + (size_t)i * 384 * kC + (size_t)(256 + t) * kC;
      for (int c = 0; c < 128; ++c) a0 += s1[c] * wr[c];
      s2[t] = inb[i * 384 + 256 + t] + a0;
    }
    __syncthreads();
    if (act) {
      float a0 = 0.f;
      const float* wr2 = tow + (size_t)i * kC * kC + (size_t)t * kC;
      for (int c = 0; c < 128; ++c) a0 += s2[c] * wr2[c];
      mout[rel * kC + t] = tob[i * kC + t] + a0;
    }
  }
}

// ---------------- k_qoff: qproj ([0,512)) + offsets ([512,2560)) ----------------
__global__ void k_qoff(const float* __restrict__ lnq1, const float* __restrict__ lnq2,
                       const float* __restrict__ qw, const float* __restrict__ o1w,
                       const float* __restrict__ o1b, const float* __restrict__ o2w,
                       __hip_bfloat16* __restrict__ qout, float* __restrict__ vgs) {
  int bx = blockIdx.x;
  if (bx < 512) {
    int bg = bx >> 4, r0 = (bx & 15) * 64;
    int str = bg >> 4, b = (bg >> 3) & 1, g = bg & 7;
    int rl = threadIdx.x & 63, dq = threadIdx.x >> 6;
    const float* lnq = str ? lnq2 : lnq1;
    const float* xr = lnq + ((size_t)(b * kN + r0 + rl)) * kC + g * 16;
    float4 x0 = *(const float4*)(xr + 0);
    float4 x1 = *(const float4*)(xr + 4);
    float4 x2 = *(const float4*)(xr + 8);
    float4 x3 = *(const float4*)(xr + 12);
    const float* wqb = qw + (size_t)str * 8192 + (size_t)g * 1024;
    __hip_bfloat16* qrow = qout + ((size_t)bg * 1024 + r0 + rl) * 64 + dq * 16;
#pragma unroll 4
    for (int dd = 0; dd < 16; ++dd) {
      int d = dq * 16 + dd;
      const float* wq = wqb + d * 16;
      float4 w0 = *(const float4*)(wq + 0);
      float4 w1 = *(const float4*)(wq + 4);
      float4 w2 = *(const float4*)(wq + 8);
      float4 w3 = *(const float4*)(wq + 12);
      float q = x0.x * w0.x + x0.y * w0.y + x0.z * w0.z + x0.w * w0.w
              + x1.x * w1.x + x1.y * w1.y + x1.z * w1.z + x1.w * w1.w
              + x2.x * w2.x + x2.y * w2.y + x2.z * w2.z + x2.w * w2.w
              + x3.x * w3.x + x3.y * w3.y + x3.z * w3.z + x3.w * w3.w;
      qrow[dd] = __float2bfloat16(q);
    }
  } else {
    int bxo = bx - 512;
    int w = threadIdx.x >> 6, lane = threadIdx.x & 63;
    int bg = bxo >> 6, j = ((bxo & 63) << 2) + w;
    int str = bg >> 4, b = (bg >> 3) & 1, g = bg & 7;
    const float* lnq = str ? lnq2 : lnq1;
    __shared__ float xr[4][96];
    int base = j * 4 - 1;
#pragma unroll
    for (int rep = 0; rep < 2; ++rep) {
      int idx = lane + rep * 64;
      if (idx < 96) {
        int r = idx >> 4, c = idx & 15, n = base + r;
        xr[w][idx] = (n >= 0 && n < kN)
                         ? lnq[((size_t)(b * kN + n)) * kC + g * 16 + c] : 0.f;
      }
    }
    const float* wq = qw + (size_t)str * 8192 + (size_t)(g * kDH + lane) * 16;
    float acc = o1b[str * 64 + lane];
#pragma unroll
    for (int k2 = 0; k2 < 6; ++k2) {
      float qv = 0.f;
#pragma unroll
      for (int c = 0; c < 16; ++c) qv += xr[w][k2 * 16 + c] * wq[c];
      acc += qv * o1w[str * 384 + lane * 6 + k2];
    }
    float ge = 0.5f * acc * (1.f + erff(acc * 0.70710678118654752440f));
    float s = wave_sum(ge * o2w[str * 64 + lane]);
    if (lane == 0)
      vgs[bg * kND + j] = 2.f * ((float)j + tanhf(s) * 4.0f) / 255.f - 1.f;
  }
}

// ---------------- grid_sample + k/v projections ----------------
__global__ void k_sample_kv(const float* __restrict__ lnkv, const float* __restrict__ vgs,
                            const float* __restrict__ kw, const float* __restrict__ vw,
                            __hip_bfloat16* __restrict__ kout,
                            __hip_bfloat16* __restrict__ vtout) {
  int w = threadIdx.x >> 6, lane = threadIdx.x & 63;
  int bg = blockIdx.x >> 6, j = ((blockIdx.x & 63) << 2) + w;
  int str = bg >> 4, b = (bg >> 3) & 1, g = bg & 7;
  __shared__ float sc[4][16];
  if (lane < 16) {
    float gr = vgs[bg * kND + j];
    float x = ((gr + 1.f) * 1024.f - 1.f) * 0.5f;
    float x0f = floorf(x);
    float w1 = x - x0f;
    int x0 = (int)x0f, x1 = x0 + 1;
    const float* src = lnkv + (size_t)b * kN * kC + g * 16 + lane;
    float v0 = (x0 >= 0 && x0 < 1024) ? src[(size_t)x0 * kC] : 0.f;
    float v1 = (x1 >= 0 && x1 < 1024) ? src[(size_t)x1 * kC] : 0.f;
    sc[w][lane] = v0 * (1.f - w1) + v1 * w1;
  }
  const float* kwr = kw + (size_t)str * 8192 + (size_t)(g * kDH + lane) * 16;
  const float* vwr = vw + (size_t)str * 8192 + (size_t)(g * kDH + lane) * 16;
  float ka = 0.f, va = 0.f;
#pragma unroll
  for (int c = 0; c < 16; ++c) { ka += sc[w][c] * kwr[c]; va += sc[w][c] * vwr[c]; }
  kout[((size_t)bg * 256 + j) * 64 + lane] = __float2bfloat16(ka);      // K[j][d]
  vtout[((size_t)bg * 64 + lane) * 256 + j] = __float2bfloat16(va);     // Vt[d][j]
}

// ---------------- MFMA flash attention, single-shot staging + LDS table ----------------
// Block = (bg, 64-row tile), 512 blocks, 4 waves. 7 barriers total.
__global__ void __launch_bounds__(256, 2)
k_attn(const __hip_bfloat16* __restrict__ q_g, const __hip_bfloat16* __restrict__ k_g,
       const __hip_bfloat16* __restrict__ vt_g, const float* __restrict__ vgs,
       const float* __restrict__ tab, float* __restrict__ aout,
       __hip_bfloat16* __restrict__ attout) {
  int bg = blockIdx.x >> 4, tile = blockIdx.x & 15;
  int str = bg >> 4;
  int i0 = tile * 64;
  int t = threadIdx.x;
  int w = t >> 6, l = t & 63;
  int lr = l & 15, lg = l >> 4;

  __shared__ __align__(16) __hip_bfloat16 Qs[64 * 72];    // Q tile, then f32 CPB table
  __shared__ __align__(16) __hip_bfloat16 KVs[256 * 72];  // K whole / Vt [64][264]
  __shared__ __align__(16) __hip_bfloat16 Ps[64 * 264];

  const float* tabs = tab + str * (kNT + 1);

  // ---- stage Q + all K (NOT wave-local: thread t stages Q row i2*32+t/8) ----
  {
    const __hip_bfloat16* qflat = q_g + ((size_t)bg * 1024 + i0) * 64;
#pragma unroll
    for (int i2 = 0; i2 < 2; ++i2) {
      int e = i2 * 2048 + t * 8;
      int r = e >> 6, c = e & 63;
      *(float4*)&Qs[r * 72 + c] = *(const float4*)(qflat + e);
    }
    const __hip_bfloat16* kflat = k_g + (size_t)bg * 256 * 64;
#pragma unroll
    for (int i2 = 0; i2 < 8; ++i2) {
      int e = i2 * 2048 + t * 8;
      int r = e >> 6, c = e & 63;
      *(float4*)&KVs[r * 72 + c] = *(const float4*)(kflat + e);
    }
  }
  __syncthreads();  // staging complete before ANY fragment read (v14 bug fix)

  short8 a0 = *(const short8*)&Qs[(w * 16 + lr) * 72 + lg * 8];
  short8 a1 = *(const short8*)&Qs[(w * 16 + lr) * 72 + 32 + lg * 8];
  __syncthreads();  // all waves' Q-frag reads done before table overwrite
  float* tabL = (float*)Qs;  // 2049 f32 = 8196 B <= 9216 B
  for (int e = t; e <= kNT; e += 256) tabL[e] = tabs[e];
  // table published by the post-QK barrier below

  // ---- QK^T: 16 col-tiles x 2 MFMA, no barriers ----
  floatx4 acc[16];
#pragma unroll
  for (int f = 0; f < 16; ++f) acc[f] = {0.f, 0.f, 0.f, 0.f};
#pragma unroll
  for (int ct = 0; ct < 16; ++ct) {
    short8 b0 = *(const short8*)&KVs[(ct * 16 + lr) * 72 + lg * 8];
    short8 b1 = *(const short8*)&KVs[(ct * 16 + lr) * 72 + 32 + lg * 8];
    acc[ct] = __builtin_amdgcn_mfma_f32_16x16x32_bf16(a0, b0, acc[ct], 0, 0, 0);
    acc[ct] = __builtin_amdgcn_mfma_f32_16x16x32_bf16(a1, b1, acc[ct], 0, 0, 0);
  }
  __syncthreads();  // K reads done; table visible

  // ---- issue V loads to registers (latency hides under softmax) ----
  float4 vr0, vr1, vr2, vr3, vr4, vr5, vr6, vr7;
  {
    const __hip_bfloat16* vflat = vt_g + (size_t)bg * 64 * 256;
    vr0 = *(const float4*)(vflat + 0 * 2048 + t * 8);
    vr1 = *(const float4*)(vflat + 1 * 2048 + t * 8);
    vr2 = *(const float4*)(vflat + 2 * 2048 + t * 8);
    vr3 = *(const float4*)(vflat + 3 * 2048 + t * 8);
    vr4 = *(const float4*)(vflat + 4 * 2048 + t * 8);
    vr5 = *(const float4*)(vflat + 5 * 2048 + t * 8);
    vr6 = *(const float4*)(vflat + 6 * 2048 + t * 8);
    vr7 = *(const float4*)(vflat + 7 * 2048 + t * 8);
  }

  // ---- bias (LDS table) + softmax (__expf); write attn f32 + P bf16 ----
  float vgl[16];
#pragma unroll
  for (int f = 0; f < 16; ++f) vgl[f] = vgs[bg * 256 + f * 16 + lr];
  float* aoutb = aout + (size_t)str * 4194304 + (size_t)(bg & 15) * 262144;
#pragma unroll
  for (int reg = 0; reg < 4; ++reg) {
    int row = w * 16 + lg * 4 + reg;
    int i = i0 + row;
    float seq = 2.f * (float)i / 1023.f - 1.f;
    float sv[16];
#pragma unroll
    for (int f = 0; f < 16; ++f)
      sv[f] = acc[f][reg] * 0.125f + cpb_lds(tabL, seq, vgl[f]);
    float m = sv[0];
#pragma unroll
    for (int f = 1; f < 16; ++f) m = fmaxf(m, sv[f]);
    m = fmaxf(m, __shfl_xor(m, 1, 64));
    m = fmaxf(m, __shfl_xor(m, 2, 64));
    m = fmaxf(m, __shfl_xor(m, 4, 64));
    m = fmaxf(m, __shfl_xor(m, 8, 64));
    float ev[16], sum = 0.f;
#pragma unroll
    for (int f = 0; f < 16; ++f) { ev[f] = __expf(sv[f] - m); sum += ev[f]; }
    sum += __shfl_xor(sum, 1, 64);
    sum += __shfl_xor(sum, 2, 64);
    sum += __shfl_xor(sum, 4, 64);
    sum += __shfl_xor(sum, 8, 64);
    float inv = 1.f / sum;
    float* arow = aoutb + (size_t)i * 256;
#pragma unroll
    for (int f = 0; f < 16; ++f) {
      float p = ev[f] * inv;
      arow[f * 16 + lr] = p;
      Ps[row * 264 + f * 16 + lr] = __float2bfloat16(p);
    }
  }

  // ---- V regs -> LDS as Vt [64][264], barrier, PV ----
  {
    int e0 = t * 8;
#pragma unroll
    for (int i2 = 0; i2 < 8; ++i2) {
      int e = i2 * 2048 + e0;
      int r = e >> 8, c = e & 255;
      float4 v = (i2 == 0) ? vr0 : (i2 == 1) ? vr1 : (i2 == 2) ? vr2 :
                 (i2 == 3) ? vr3 : (i2 == 4) ? vr4 : (i2 == 5) ? vr5 :
                 (i2 == 6) ? vr6 : vr7;
      *(float4*)&KVs[r * 264 + c] = v;
    }
  }
  __syncthreads();

  floatx4 oacc[4];
#pragma unroll
  for (int dt = 0; dt < 4; ++dt) oacc[dt] = {0.f, 0.f, 0.f, 0.f};
#pragma unroll
  for (int ks = 0; ks < 8; ++ks) {
    short8 pa = *(const short8*)&Ps[(w * 16 + lr) * 264 + ks * 32 + lg * 8];
#pragma unroll
    for (int dt = 0; dt < 4; ++dt) {
      short8 b = *(const short8*)&KVs[(dt * 16 + lr) * 264 + ks * 32 + lg * 8];
      oacc[dt] = __builtin_amdgcn_mfma_f32_16x16x32_bf16(pa, b, oacc[dt], 0, 0, 0);
    }
  }
  {
    int b = (bg >> 3) & 1, g = bg & 7;
    __hip_bfloat16* ab = attout + ((size_t)(str * 2 + b) * 1024) * 512 + (size_t)g * 64;
#pragma unroll
    for (int dt = 0; dt < 4; ++dt)
#pragma unroll
      for (int reg = 0; reg < 4; ++reg) {
        int row = w * 16 + lg * 4 + reg;
        ab[(size_t)(i0 + row) * 512 + dt * 16 + lr] = __float2bfloat16(oacc[dt][reg]);
      }
  }
}

// ---------------- MFMA oproj + residual + fuse + meanz (merged) ----------------
__global__ void __launch_bounds__(256, 2)
k_oproj_fuse(const __hip_bfloat16* __restrict__ aog, const __hip_bfloat16* __restrict__ owb,
             const float* __restrict__ ob,
             const float* __restrict__ x1_0, const float* __restrict__ x1_1,
             const __hip_bfloat16* __restrict__ fwb, const float* __restrict__ fb,
             const float* __restrict__ ng, const float* __restrict__ nb,
             const float* __restrict__ tfng, const float* __restrict__ tfnb,
             const float* __restrict__ mout, float* __restrict__ partial) {
  int tok0 = blockIdx.x * 16;
  int t = threadIdx.x;
  int w = t >> 6, l = t & 63;
  int lr = l & 15, lg = l >> 4;
  int nt0 = w * 2;

  __shared__ __align__(16) unsigned char smem[16 * 280 * 2];
  __shared__ float red[4][128];
  __hip_bfloat16* xos = (__hip_bfloat16*)smem;
  float* fs = (float*)smem;

  for (int s = 0; s < 2; ++s) {
    const __hip_bfloat16* arow = aog + ((size_t)(s * 2048 + tok0 + lr)) * 512 + lg * 8;
    const __hip_bfloat16* wb0 = owb + (size_t)s * 65536 + (size_t)((nt0 + 0) * 16 + lr) * 512 + lg * 8;
    const __hip_bfloat16* wb1 = owb + (size_t)s * 65536 + (size_t)((nt0 + 1) * 16 + lr) * 512 + lg * 8;
    floatx4 acc0 = {0.f, 0.f, 0.f, 0.f}, acc1 = {0.f, 0.f, 0.f, 0.f};
#pragma unroll
    for (int ks = 0; ks < 16; ++ks) {
      short8 a  = *(const short8*)(arow + ks * 32);
      short8 b0 = *(const short8*)(wb0 + ks * 32);
      short8 b1 = *(const short8*)(wb1 + ks * 32);
      acc0 = __builtin_amdgcn_mfma_f32_16x16x32_bf16(a, b0, acc0, 0, 0, 0);
      acc1 = __builtin_amdgcn_mfma_f32_16x16x32_bf16(a, b1, acc1, 0, 0, 0);
    }
    const float* x1 = s ? x1_1 : x1_0;
    float bias0 = ob[s * 128 + nt0 * 16 + lr];
    float bias1 = ob[s * 128 + (nt0 + 1) * 16 + lr];
#pragma unroll
    for (int reg = 0; reg < 4; ++reg) {
      int row = lg * 4 + reg;
      size_t xi = (size_t)(tok0 + row) * 128;
      xos[row * 280 + s * 128 + nt0 * 16 + lr] =
          __float2bfloat16(acc0[reg] + x1[xi + nt0 * 16 + lr] + bias0);
      xos[row * 280 + s * 128 + (nt0 + 1) * 16 + lr] =
          __float2bfloat16(acc1[reg] + x1[xi + (nt0 + 1) * 16 + lr] + bias1);
    }
  }
  __syncthreads();

  floatx4 f0 = {0.f, 0.f, 0.f, 0.f}, f1 = {0.f, 0.f, 0.f, 0.f};
  const __hip_bfloat16* fb0 = fwb + (size_t)((nt0 + 0) * 16 + lr) * 256 + lg * 8;
  const __hip_bfloat16* fb1 = fwb + (size_t)((nt0 + 1) * 16 + lr) * 256 + lg * 8;
#pragma unroll
  for (int ks = 0; ks < 8; ++ks) {
    short8 a  = *(const short8*)&xos[lr * 280 + ks * 32 + lg * 8];
    short8 b0 = *(const short8*)(fb0 + ks * 32);
    short8 b1 = *(const short8*)(fb1 + ks * 32);
    f0 = __builtin_amdgcn_mfma_f32_16x16x32_bf16(a, b0, f0, 0, 0, 0);
    f1 = __builtin_amdgcn_mfma_f32_16x16x32_bf16(a, b1, f1, 0, 0, 0);
  }
  __syncthreads();

  {
    float fbias0 = fb[nt0 * 16 + lr], fbias1 = fb[(nt0 + 1) * 16 + lr];
#pragma unroll
    for (int reg = 0; reg < 4; ++reg) {
      int row = lg * 4 + reg;
      fs[row * 132 + w * 32 + lr]      = f0[reg] + fbias0;
      fs[row * 132 + w * 32 + 16 + lr] = f1[reg] + fbias1;
    }
  }
  __syncthreads();

  int b = tok0 >> 10, chunk = (tok0 & 1023) >> 4;
  float g1a = ng[l], b1a = nb[l], g1b = ng[l + 64], b1b = nb[l + 64];
  float mo0a = mout[b * 128 + l], mo0b = mout[b * 128 + l + 64];
  float mo1a = mout[(2 + b) * 128 + l], mo1b = mout[(2 + b) * 128 + l + 64];
  float g20a = tfng[l], b20a = tfnb[l], g20b = tfng[l + 64], b20b = tfnb[l + 64];
  float g21a = tfng[128 + l], b21a = tfnb[128 + l];
  float g21b = tfng[192 + l], b21b = tfnb[192 + l];
  float acc0a = 0.f, acc0b = 0.f, acc1a = 0.f, acc1b = 0.f;
#pragma unroll
  for (int it = 0; it < 4; ++it) {
    int tok = it * 4 + w;
    float xa = fs[tok * 132 + l], xb = fs[tok * 132 + l + 64];
    float m1 = wave_sum(xa + xb) * (1.f / kC);
    float da = xa - m1, db = xb - m1;
    float v1 = wave_sum(da * da + db * db) * (1.f / kC);
    float r1 = rsqrtf(v1 + 1e-5f);
    float ba = da * r1 * g1a + b1a, bb = db * r1 * g1b + b1b;
    {
      float za = ba + mo0a, zb = bb + mo0b;
      float m2 = wave_sum(za + zb) * (1.f / kC);
      float ea = za - m2, eb = zb - m2;
      float v2 = wave_sum(ea * ea + eb * eb) * (1.f / kC);
      float r2 = rsqrtf(v2 + 1e-5f);
      acc0a += ea * r2 * g20a + b20a;
      acc0b += eb * r2 * g20b + b20b;
    }
    {
      float za = ba + mo1a, zb = bb + mo1b;
      float m2 = wave_sum(za + zb) * (1.f / kC);
      float ea = za - m2, eb = zb - m2;
      float v2 = wave_sum(ea * ea + eb * eb) * (1.f / kC);
      float r2 = rsqrtf(v2 + 1e-5f);
      acc1a += ea * r2 * g21a + b21a;
      acc1b += eb * r2 * g21b + b21b;
    }
  }
  red[w][l] = acc0a; red[w][l + 64] = acc0b;
  __syncthreads();
  if (w == 0) {
    float* pr = partial + ((size_t)(b)*64 + chunk) * kC;
    pr[l]      = red[0][l] + red[1][l] + red[2][l] + red[3][l];
    pr[l + 64] = red[0][l + 64] + red[1][l + 64] + red[2][l + 64] + red[3][l + 64];
  }
  __syncthreads();
  red[w][l] = acc1a; red[w][l + 64] = acc1b;
  __syncthreads();
  if (w == 0) {
    float* pr = partial + ((size_t)(2 + b) * 64 + chunk) * kC;
    pr[l]      = red[0][l] + red[1][l] + red[2][l] + red[3][l];
    pr[l + 64] = red[0][l + 64] + red[1][l + 64] + red[2][l + 64] + red[3][l + 64];
  }
}

__global__ void k_final(const float* __restrict__ partial, const float* __restrict__ pw,
                        const float* __restrict__ pb, float* __restrict__ out) {
  int ib = blockIdx.x;
  int i = ib >> 1, t = threadIdx.x;
  int c = t & 127, half = t >> 7;
  float a = 0.f;
  for (int ch = half * 32; ch < half * 32 + 32; ++ch)
    a += partial[((size_t)ib * 64 + ch) * kC + c];
  __shared__ float s[256];
  s[half * 128 + c] = a;
  __syncthreads();
  if (t < 128) s[t] = (s[t] + s[128 + t]) * (1.f / (float)kN);
  __syncthreads();
  if (t < 128) {
    float a0 = 0.f;
    const float* wr = pw + (size_t)i * kC * kC + (size_t)t * kC;
    for (int cc = 0; cc < 128; ++cc) a0 += s[cc] * wr[cc];
    out[ib * 128 + t] = tanhf(pb[i * kC + t] + a0);
  }
}

extern "C" void kernel_launch(void* const* d_in, const int* in_sizes, int n_in,
                              void* d_out, int out_size, void* d_ws, size_t ws_size,
                              hipStream_t stream) {
  const float* x1_0   = (const float*)d_in[0];
  const float* x1_1   = (const float*)d_in[1];
  const float* x2     = (const float*)d_in[2];
  const float* norm_g = (const float*)d_in[3];
  const float* norm_b = (const float*)d_in[4];
  const float* d_qw   = (const float*)d_in[5];
  const float* d_kw   = (const float*)d_in[6];
  const float* d_vw   = (const float*)d_in[7];
  const float* d_ow   = (const float*)d_in[8];
  const float* d_ob   = (const float*)d_in[9];
  const float* d_o1w  = (const float*)d_in[10];
  const float* d_o1b  = (const float*)d_in[11];
  const float* d_o2w  = (const float*)d_in[12];
  const float* c_w1   = (const float*)d_in[13];
  const float* c_b1   = (const float*)d_in[14];
  const float* c_w2   = (const float*)d_in[15];
  const float* c_b2   = (const float*)d_in[16];
  const float* c_w3   = (const float*)d_in[17];
  const float* c_b3   = (const float*)d_in[18];
  const float* fus_w  = (const float*)d_in[19];
  const float* fus_b  = (const float*)d_in[20];
  const float* tf_ng  = (const float*)d_in[21];
  const float* tf_nb  = (const float*)d_in[22];
  const float* tf_inw = (const float*)d_in[23];
  const float* tf_inb = (const float*)d_in[24];
  const float* tf_ow  = (const float*)d_in[25];
  const float* tf_ob  = (const float*)d_in[26];
  const float* tf_pw  = (const float*)d_in[27];
  const float* tf_pb  = (const float*)d_in[28];

  float* ws = (float*)d_ws;
  float* out = (float*)d_out;
  float* lnkv = ws + W_LNKV;
  float* lnq1 = ws + W_LNQ1; float* lnq2 = ws + W_LNQ2;
  __hip_bfloat16* qb  = (__hip_bfloat16*)(ws + W_Q);
  __hip_bfloat16* kb  = (__hip_bfloat16*)(ws + W_K);
  __hip_bfloat16* vtb = (__hip_bfloat16*)(ws + W_VT);
  float* vgsw = ws + W_VGS;
  __hip_bfloat16* aob = (__hip_bfloat16*)(ws + W_AO);
  float* tab = ws + W_TAB;
  float* moutp = ws + W_MOUT; float* partp = ws + W_PART;
  __hip_bfloat16* owb = (__hip_bfloat16*)(ws + W_OWB);
  __hip_bfloat16* fwb = (__hip_bfloat16*)(ws + W_FWB);

  // output: f1(256) | f2(256) | a1(2*8*1024*256) | a2(same), all f32
  float* aoutb = out + 512;

  k_prep<<<2198, 256, 0, stream>>>(d_ow, fus_w, owb, fwb,
                                   x1_0, x1_1, x2, lnq1, lnq2, lnkv, norm_g, norm_b,
                                   c_w1, c_b1, c_w2, c_b2, c_w3, c_b3, tab,
                                   tf_ng, tf_nb, tf_inw, tf_inb, tf_ow, tf_ob, moutp);
  k_qoff<<<2560, 256, 0, stream>>>(lnq1, lnq2, d_qw, d_o1w, d_o1b, d_o2w, qb, vgsw);
  k_sample_kv<<<2048, 256, 0, stream>>>(lnkv, vgsw, d_kw, d_vw, kb, vtb);
  k_attn<<<512, 256, 0, stream>>>(qb, kb, vtb, vgsw, tab, aoutb, aob);
  k_oproj_fuse<<<128, 256, 0, stream>>>(aob, owb, d_ob, x1_0, x1_1, fwb, fus_b,
                                        norm_g, norm_b, tf_ng, tf_nb, moutp, partp);
  k_final<<<4, 256, 0, stream>>>(partp, tf_pw, tf_pb, out);

  (void)in_sizes; (void)n_in; (void)out_size; (void)ws_size;
}